// Round 1
// baseline (1705.009 us; speedup 1.0000x reference)
//
#include <hip/hip_runtime.h>
#include <hip/hip_bf16.h>

// ============================================================================
// NexToU encoder block (Grapher + FFN), B=2 C=96 D=32 H=64 W=64, K=2, f32 I/O.
//
// Pipeline (all norm stats computed at runtime; norms folded into affine
// coefs A[c],B[c] applied in the *consumer* kernel's load path):
//   k1  convk fc1 : x (f32) -> y1 (bf16), BN1 stats
//   k2  finalize  : c1 = (A1,B1)
//   k3  mrk       : y1,(c1) -> xj = h1 - min3  (bf16)
//   k4  convk g   : [h1;xj] -> yg (bf16), IN stats (per b,c)
//   k5  finalize  : c2
//   k6  convk fc2 : lrelu(A2*yg+B2) -> y2 (bf16), BN2 stats
//   k7  finalize  : c3
//   k8  ewx2      : x2 = A3*y2+B3 + x   (bf16)
//   k9  convk f1  : x2 -> y3 (bf16), BNf1 stats (384 ch)
//   k10 finalize  : c4
//   k11 convk f2  : lrelu(A4*y3+B4) -> y4 (bf16), BNf2 stats
//   k12 finalize  : c5
//   k13 ewout     : out = A5*y4+B5 + x2   (f32)
//
// Workspace layout (bytes), with lifetime reuse (~302 MB total):
//   [0, 201326592)          : y1 | xj | yg   then y3 (y1/xj/yg dead by k6)
//   [201326592, 251658240)  : y2, later y4 (y2 dead after k8)
//   [251658240, 301989888)  : x2
//   [301989888, +80KB)      : stats slots (2048 f32 each) s1..s5, c1..c5
// ============================================================================

typedef __hip_bfloat16 bf16;
#define DEV static __device__ __forceinline__

constexpr int Bq = 2, Cq = 96, Dq = 32, Hq = 64, Wq = 64;
constexpr int Sq = Dq * Hq * Wq;       // 131072
constexpr int NVq = Bq * Sq;           // 262144 voxels
constexpr float EPSq = 1e-5f;
constexpr float SLOPEq = 0.2f;

constexpr int TPB = 256;
constexpr int CO_T = 32;               // output channels per block
constexpr int VPT = 4;                 // voxels per thread
constexpr int VOX_B = TPB * VPT;       // 1024 voxels per block

DEV float b2f(bf16 v) { return __bfloat162float(v); }
DEV bf16 f2b(float v) { return __float2bfloat16(v); }

struct BF4 { bf16 a, b, c, d; };
DEV float4 ldbf4(const bf16* p) {
    BF4 v = *reinterpret_cast<const BF4*>(p);
    return make_float4(b2f(v.a), b2f(v.b), b2f(v.c), b2f(v.d));
}
DEV void stbf4(bf16* p, float x, float y, float z, float w) {
    BF4 o; o.a = f2b(x); o.b = f2b(y); o.c = f2b(z); o.d = f2b(w);
    *reinterpret_cast<BF4*>(p) = o;
}
DEV float lrelu(float t) { return t >= 0.f ? t : SLOPEq * t; }

// ---------------------------------------------------------------------------
// Generic 1x1x1 conv (per-voxel GEMM) with fused input transform + stats.
// MODE: 0 = plain f32 input
//       1 = channels [0,96): A1*bf(y1)+B1 ; [96,192): bf(xj)   (Grapher concat)
//       2 = per-(b,c) affine + lrelu (InstanceNorm -> LeakyReLU fold)
//       3 = plain bf16 input
//       4 = per-c affine + lrelu (BN -> LeakyReLU fold)
// Stats: per output channel (PER_B=false) or per (b, channel) (PER_B=true).
//   stat[sidx] += sum(y);  stat[1024 + sidx] += sum(y^2)
// ---------------------------------------------------------------------------
template <int CI, int MODE, bool PER_B>
__global__ __launch_bounds__(TPB)
void convk(const float* __restrict__ pF,
           const bf16*  __restrict__ pB,
           const bf16*  __restrict__ pB2,
           const float* __restrict__ cA,
           const float* __restrict__ cBv,
           const float* __restrict__ wgt,
           const float* __restrict__ bias,
           int CO,
           bf16* __restrict__ outp,
           float* __restrict__ stat)
{
    __shared__ float wl[CO_T * CI];
    __shared__ float pstat[TPB / 64][CO_T][2];

    const int og = blockIdx.y;
    const int vb = blockIdx.x * VOX_B;
    const int b  = vb / Sq;
    const int s0 = (vb % Sq) + (int)threadIdx.x * VPT;

    for (int i = threadIdx.x; i < CO_T * CI; i += TPB)
        wl[i] = wgt[(size_t)(og * CO_T + i / CI) * CI + (i % CI)];
    __syncthreads();

    float acc[CO_T][VPT];
#pragma unroll
    for (int o = 0; o < CO_T; ++o) {
        float bb = bias[og * CO_T + o];
#pragma unroll
        for (int v = 0; v < VPT; ++v) acc[o][v] = bb;
    }

    for (int c = 0; c < CI; ++c) {
        float v0, v1, v2, v3;
        if constexpr (MODE == 0) {
            float4 r = *reinterpret_cast<const float4*>(&pF[(size_t)(b * CI + c) * Sq + s0]);
            v0 = r.x; v1 = r.y; v2 = r.z; v3 = r.w;
        } else if constexpr (MODE == 1) {
            if (c < Cq) {
                float4 r = ldbf4(&pB[(size_t)(b * Cq + c) * Sq + s0]);
                float a = cA[c], d = cBv[c];
                v0 = fmaf(a, r.x, d); v1 = fmaf(a, r.y, d);
                v2 = fmaf(a, r.z, d); v3 = fmaf(a, r.w, d);
            } else {
                float4 r = ldbf4(&pB2[(size_t)(b * Cq + (c - Cq)) * Sq + s0]);
                v0 = r.x; v1 = r.y; v2 = r.z; v3 = r.w;
            }
        } else if constexpr (MODE == 2) {
            float4 r = ldbf4(&pB[(size_t)(b * CI + c) * Sq + s0]);
            float a = cA[b * CI + c], d = cBv[b * CI + c];
            v0 = lrelu(fmaf(a, r.x, d)); v1 = lrelu(fmaf(a, r.y, d));
            v2 = lrelu(fmaf(a, r.z, d)); v3 = lrelu(fmaf(a, r.w, d));
        } else if constexpr (MODE == 3) {
            float4 r = ldbf4(&pB[(size_t)(b * CI + c) * Sq + s0]);
            v0 = r.x; v1 = r.y; v2 = r.z; v3 = r.w;
        } else {  // MODE 4
            float4 r = ldbf4(&pB[(size_t)(b * CI + c) * Sq + s0]);
            float a = cA[c], d = cBv[c];
            v0 = lrelu(fmaf(a, r.x, d)); v1 = lrelu(fmaf(a, r.y, d));
            v2 = lrelu(fmaf(a, r.z, d)); v3 = lrelu(fmaf(a, r.w, d));
        }
#pragma unroll
        for (int o = 0; o < CO_T; ++o) {
            float w = wl[o * CI + c];
            acc[o][0] = fmaf(w, v0, acc[o][0]);
            acc[o][1] = fmaf(w, v1, acc[o][1]);
            acc[o][2] = fmaf(w, v2, acc[o][2]);
            acc[o][3] = fmaf(w, v3, acc[o][3]);
        }
    }

    const int lane = threadIdx.x & 63, wid = threadIdx.x >> 6;
#pragma unroll
    for (int o = 0; o < CO_T; ++o) {
        int oc = og * CO_T + o;
        stbf4(&outp[(size_t)(b * CO + oc) * Sq + s0],
              acc[o][0], acc[o][1], acc[o][2], acc[o][3]);
        float sm = acc[o][0] + acc[o][1] + acc[o][2] + acc[o][3];
        float sq = acc[o][0] * acc[o][0] + acc[o][1] * acc[o][1] +
                   acc[o][2] * acc[o][2] + acc[o][3] * acc[o][3];
#pragma unroll
        for (int off = 32; off > 0; off >>= 1) {
            sm += __shfl_down(sm, off);
            sq += __shfl_down(sq, off);
        }
        if (lane == 0) { pstat[wid][o][0] = sm; pstat[wid][o][1] = sq; }
    }
    __syncthreads();
    if (threadIdx.x < CO_T * 2) {
        int o = threadIdx.x % CO_T;
        int which = threadIdx.x / CO_T;
        float v = pstat[0][o][which] + pstat[1][o][which] +
                  pstat[2][o][which] + pstat[3][o][which];
        int oc = og * CO_T + o;
        int sidx = PER_B ? (b * CO + oc) : oc;
        atomicAdd(&stat[which * 1024 + sidx], v);
    }
}

// ---------------------------------------------------------------------------
// stats -> affine coefs:  A = g*rsqrt(var+eps), B = be - mean*A
// ---------------------------------------------------------------------------
__global__ void finalize_k(const float* __restrict__ st, float* __restrict__ cf,
                           const float* __restrict__ g, const float* __restrict__ be,
                           int n, int nc, float invN)
{
    int i = blockIdx.x * blockDim.x + threadIdx.x;
    if (i >= n) return;
    float m   = st[i] * invN;
    float var = st[1024 + i] * invN - m * m;
    float A   = g[i % nc] * rsqrtf(var + EPSq);
    cf[i]        = A;
    cf[1024 + i] = fmaf(-m, A, be[i % nc]);
}

// ---------------------------------------------------------------------------
// MRConv aggregation: one block per (b,c) plane [32,64,64].
//   xj = h1 - min( Wmin[d][h][w&1], Hmin[d][w][h&1], Dmin[h][w][d&1] )
// where each *min is the min of h1 over the residue class (mod 2) along that
// axis. h1 = A1*bf(y1)+B1 applied on the fly. LDS = 32+16+16 = 64 KB.
// ---------------------------------------------------------------------------
__global__ __launch_bounds__(1024)
void mrk(const bf16* __restrict__ y1,
         const float* __restrict__ cA, const float* __restrict__ cBv,
         bf16* __restrict__ xj)
{
    __shared__ float dmin[64][64][2];   // [h][w][d&1]  32 KB
    __shared__ float hmin[32][64][2];   // [d][w][h&1]  16 KB
    __shared__ float wmin[32][64][2];   // [d][h][w&1]  16 KB

    const int bc = blockIdx.x;          // b*96 + c
    const int c  = bc % Cq;
    const float A = cA[c], Bv = cBv[c];
    const bf16* p = y1 + (size_t)bc * Sq;
    const int tid = threadIdx.x, lane = tid & 63, wid = tid >> 6;

    // Phase A: D-axis residue mins. thread -> (h = wid+16i, w = lane)
    for (int i = 0; i < 4; ++i) {
        int h = wid + 16 * i;
        float e = 1e30f, o = 1e30f;
        for (int d = 0; d < Dq; d += 2) {
            float v0 = fmaf(A, b2f(p[(size_t)d * 4096 + h * 64 + lane]), Bv);
            float v1 = fmaf(A, b2f(p[(size_t)(d + 1) * 4096 + h * 64 + lane]), Bv);
            e = fminf(e, v0); o = fminf(o, v1);
        }
        dmin[h][lane][0] = e; dmin[h][lane][1] = o;
    }
    // Phase B: per-warp rows d = wid, wid+16 -> W-axis and H-axis mins
    for (int i = 0; i < 2; ++i) {
        int d = wid + 16 * i;
        float cE = 1e30f, cO = 1e30f;
        for (int h = 0; h < Hq; ++h) {
            float v = fmaf(A, b2f(p[(size_t)d * 4096 + h * 64 + lane]), Bv);
            if (h & 1) cO = fminf(cO, v); else cE = fminf(cE, v);
            float m = v;  // reduce min within lane-parity class (xor 2..32)
            m = fminf(m, __shfl_xor(m, 2));
            m = fminf(m, __shfl_xor(m, 4));
            m = fminf(m, __shfl_xor(m, 8));
            m = fminf(m, __shfl_xor(m, 16));
            m = fminf(m, __shfl_xor(m, 32));
            if (lane < 2) wmin[d][h][lane] = m;
        }
        hmin[d][lane][0] = cE; hmin[d][lane][1] = cO;
    }
    __syncthreads();
    // Phase C: write xj
    bf16* xp = xj + (size_t)bc * Sq;
    for (int base = tid * 4; base < Sq; base += 1024 * 4) {
        float4 r = ldbf4(&p[base]);
        int w0 = base & 63, h = (base >> 6) & 63, d = base >> 12;
        float vv[4] = { fmaf(A, r.x, Bv), fmaf(A, r.y, Bv),
                        fmaf(A, r.z, Bv), fmaf(A, r.w, Bv) };
        float ov[4];
#pragma unroll
        for (int j = 0; j < 4; ++j) {
            int w = w0 + j;
            float m = fminf(fminf(wmin[d][h][w & 1], hmin[d][w][h & 1]),
                            dmin[h][w][d & 1]);
            ov[j] = vv[j] - m;
        }
        stbf4(&xp[base], ov[0], ov[1], ov[2], ov[3]);
    }
}

// ---------------------------------------------------------------------------
// x2 = A3*bf(y2)+B3 + x   (bf16 out)
// ---------------------------------------------------------------------------
__global__ __launch_bounds__(256)
void ewx2_k(const bf16* __restrict__ y2, const float* __restrict__ cf,
            const float* __restrict__ x, bf16* __restrict__ x2)
{
    size_t i = ((size_t)blockIdx.x * 256 + threadIdx.x) * 4;
    int c = (int)((i / (size_t)Sq) % Cq);
    float A = cf[c], Bv = cf[1024 + c];
    float4 r = ldbf4(&y2[i]);
    float4 xv = *reinterpret_cast<const float4*>(&x[i]);
    stbf4(&x2[i], fmaf(A, r.x, Bv) + xv.x, fmaf(A, r.y, Bv) + xv.y,
                  fmaf(A, r.z, Bv) + xv.z, fmaf(A, r.w, Bv) + xv.w);
}

// ---------------------------------------------------------------------------
// out = A5*bf(y4)+B5 + bf(x2)   (f32 out)
// ---------------------------------------------------------------------------
__global__ __launch_bounds__(256)
void ewout_k(const bf16* __restrict__ y4, const float* __restrict__ cf,
             const bf16* __restrict__ x2, float* __restrict__ outp)
{
    size_t i = ((size_t)blockIdx.x * 256 + threadIdx.x) * 4;
    int c = (int)((i / (size_t)Sq) % Cq);
    float A = cf[c], Bv = cf[1024 + c];
    float4 r = ldbf4(&y4[i]);
    float4 s = ldbf4(&x2[i]);
    float4 o = make_float4(fmaf(A, r.x, Bv) + s.x, fmaf(A, r.y, Bv) + s.y,
                           fmaf(A, r.z, Bv) + s.z, fmaf(A, r.w, Bv) + s.w);
    *reinterpret_cast<float4*>(&outp[i]) = o;
}

// ===========================================================================
extern "C" void kernel_launch(void* const* d_in, const int* in_sizes, int n_in,
                              void* d_out, int out_size, void* d_ws, size_t ws_size,
                              hipStream_t stream)
{
    (void)in_sizes; (void)n_in; (void)out_size; (void)ws_size;

    const float* x      = (const float*)d_in[0];
    const float* w_fc1  = (const float*)d_in[1];
    const float* b_fc1  = (const float*)d_in[2];
    const float* g_bn1  = (const float*)d_in[3];
    const float* be_bn1 = (const float*)d_in[4];
    const float* w_g    = (const float*)d_in[5];
    const float* b_g    = (const float*)d_in[6];
    const float* g_in   = (const float*)d_in[7];
    const float* be_in  = (const float*)d_in[8];
    const float* w_fc2  = (const float*)d_in[9];
    const float* b_fc2  = (const float*)d_in[10];
    const float* g_bn2  = (const float*)d_in[11];
    const float* be_bn2 = (const float*)d_in[12];
    const float* w_f1   = (const float*)d_in[13];
    const float* b_f1   = (const float*)d_in[14];
    const float* g_bnf1 = (const float*)d_in[15];
    const float* be_bnf1= (const float*)d_in[16];
    const float* w_f2   = (const float*)d_in[17];
    const float* b_f2   = (const float*)d_in[18];
    const float* g_bnf2 = (const float*)d_in[19];
    const float* be_bnf2= (const float*)d_in[20];
    float* outp = (float*)d_out;

    char* W = (char*)d_ws;
    bf16* y1 = (bf16*)(W);
    bf16* xj = (bf16*)(W + 50331648ull);
    bf16* yg = (bf16*)(W + 100663296ull);
    bf16* y3 = (bf16*)(W);                    // reuses y1|xj|yg region
    bf16* y2 = (bf16*)(W + 201326592ull);
    bf16* y4 = (bf16*)(W + 201326592ull);     // reuses y2 region
    bf16* x2 = (bf16*)(W + 251658240ull);
    float* st = (float*)(W + 301989888ull);
    float *s1 = st,          *s2 = st + 2048, *s3 = st + 4096,
          *s4 = st + 6144,   *s5 = st + 8192;
    float *c1 = st + 10240,  *c2 = st + 12288, *c3 = st + 14336,
          *c4 = st + 16384,  *c5 = st + 18432;

    hipMemsetAsync(st, 0, 5 * 2048 * sizeof(float), stream);

    dim3 blk(TPB);
    const int vbk = NVq / VOX_B;  // 256
    const float invBN = 1.f / (float)NVq, invIN = 1.f / (float)Sq;

    // Grapher
    convk<96, 0, false><<<dim3(vbk, 3), blk, 0, stream>>>(
        x, nullptr, nullptr, nullptr, nullptr, w_fc1, b_fc1, 96, y1, s1);
    finalize_k<<<dim3(1), dim3(96), 0, stream>>>(s1, c1, g_bn1, be_bn1, 96, 96, invBN);
    mrk<<<dim3(Bq * Cq), dim3(1024), 0, stream>>>(y1, c1, c1 + 1024, xj);
    convk<192, 1, true><<<dim3(vbk, 6), blk, 0, stream>>>(
        nullptr, y1, xj, c1, c1 + 1024, w_g, b_g, 192, yg, s2);
    finalize_k<<<dim3(2), dim3(192), 0, stream>>>(s2, c2, g_in, be_in, 384, 192, invIN);
    convk<192, 2, false><<<dim3(vbk, 3), blk, 0, stream>>>(
        nullptr, yg, nullptr, c2, c2 + 1024, w_fc2, b_fc2, 96, y2, s3);
    finalize_k<<<dim3(1), dim3(96), 0, stream>>>(s3, c3, g_bn2, be_bn2, 96, 96, invBN);
    ewx2_k<<<dim3(24576), blk, 0, stream>>>(y2, c3, x, x2);

    // FFN
    convk<96, 3, false><<<dim3(vbk, 12), blk, 0, stream>>>(
        nullptr, x2, nullptr, nullptr, nullptr, w_f1, b_f1, 384, y3, s4);
    finalize_k<<<dim3(2), dim3(192), 0, stream>>>(s4, c4, g_bnf1, be_bnf1, 384, 384, invBN);
    convk<384, 4, false><<<dim3(vbk, 3), blk, 0, stream>>>(
        nullptr, y3, nullptr, c4, c4 + 1024, w_f2, b_f2, 96, y4, s5);
    finalize_k<<<dim3(1), dim3(96), 0, stream>>>(s5, c5, g_bnf2, be_bnf2, 96, 96, invBN);
    ewout_k<<<dim3(24576), blk, 0, stream>>>(y4, c5, x2, outp);
}

// Round 2
// 672.673 us; speedup vs baseline: 2.5347x; 2.5347x over previous
//
#include <hip/hip_runtime.h>
#include <hip/hip_bf16.h>

// ============================================================================
// NexToU encoder block, MFMA bf16 version. All activations in [voxel][channel]
// (channel-fast) layout so every 1x1x1-conv GEMM has K-contiguous operands.
//
//  wprep : weights f32 [CO][CI] -> bf16 [CO][KP] (K zero-padded to mult of 64)
//  tin   : x f32 [b][c][s] -> xT bf16 [v][96]         (LDS transpose)
//  conv fc1 (MFMA)  xT -> y1, BN1 partials
//  mr p1a/p1b       y1(+c1 affine) -> dmin/hmin residue-min fields
//  mr p2            y1 -> hx = [h1 ; xj]  [v][192]
//  conv g  (MFMA)   hx -> yg, IN partials (per b,c)
//  conv fc2 (MFMA, loader = lrelu(A2*yg+B2) per (b,c))  -> y2, BN2 partials
//  ewx2  : x2 = A3*y2+B3 + x   (transpose-reads x)     [v][96] bf16
//  conv f1 (MFMA)   x2 -> y3 [v][384], BNf1 partials
//  conv f2 (MFMA, loader = lrelu(A4*y3+B4))            -> y4, BNf2 partials
//  tout  : out = A5*y4+B5 + x2, transposed back to f32 [b][c][s]
// ============================================================================

typedef __hip_bfloat16 bf16;
typedef __attribute__((ext_vector_type(8))) short short8;
typedef __attribute__((ext_vector_type(4))) float f4;

#define DEV static __device__ __forceinline__

constexpr int Sq  = 131072;   // D*H*W
constexpr int NVq = 262144;   // B*S

DEV float bu2f(unsigned short u) { return __uint_as_float(((unsigned)u) << 16); }
DEV unsigned short f2bu(float f) {
    unsigned i = __float_as_uint(f);
    unsigned r = i + 0x7FFFu + ((i >> 16) & 1u);   // RNE (finite inputs only)
    return (unsigned short)(r >> 16);
}
DEV void glds16(const void* g, void* l) {
    __builtin_amdgcn_global_load_lds(
        (const __attribute__((address_space(1))) unsigned*)g,
        (__attribute__((address_space(3))) unsigned*)l, 16, 0, 0);
}

// ---------------------------------------------------------------------------
// MFMA conv: Y[v][n] = sum_k A[v][k] * W[n][k] + bias[n], with fused stats.
// BM=128 (4 waves x 32 rows), BN = 96 or 192 (gy splits CO), BK=64.
// AMODE: 0 plain (global_load_lds), 1 per-c affine+lrelu (reg-staged),
//        2 per-(b,c) affine+lrelu (reg-staged).
// LDS layout: A [128 rows][8 x 16B chunks], chunk u of row v stored at unit
// u^(v&7)  -> conflict-free ds_read_b128 fragments. Same for B.
// ---------------------------------------------------------------------------
template<int CIRB, int KP, int CO, int BN, int AMODE, bool PERB>
__global__ __launch_bounds__(256)
void conv_k(const char* __restrict__ Ab, const char* __restrict__ Wb,
            const float* __restrict__ bias,
            const float* __restrict__ cfA, const float* __restrict__ cfB,
            bf16* __restrict__ Y, float* __restrict__ part)
{
    constexpr int NSTEP = KP / 64;
    constexpr int NF = BN / 16;
    constexpr int BI = BN / 8;
    __shared__ __align__(16) char smem[16384 + BN * 128];
    char* As = smem;
    char* Bs = smem + 16384;

    const int tid = threadIdx.x;
    const int lane = tid & 63, wid = tid >> 6, l16 = lane & 15, lhi = lane >> 4;
    const int gm = blockIdx.x, gy = blockIdx.y;
    const int v0 = gm * 128;
    const int b = gm >> 10;          // 1024 M-blocks per batch sample
    const int n0g = gy * BN;

    f4 acc[2][NF];
#pragma unroll
    for (int nf = 0; nf < NF; ++nf) {
        float bb = bias[n0g + nf * 16 + l16];
        f4 t = {bb, bb, bb, bb};
        acc[0][nf] = t; acc[1][nf] = t;
    }

    for (int s = 0; s < NSTEP; ++s) {
        // ---- stage B tile (weights, bf16-padded, plain)
        for (int i = wid; i < BI; i += 4) {
            int o = i * 8 + (lane >> 3);
            glds16(Wb + (size_t)(n0g + o) * (KP * 2) + s * 128 + (((lane & 7) ^ (o & 7)) << 4),
                   Bs + i * 1024);
        }
        // ---- stage A tile
        if constexpr (AMODE == 0) {
            for (int i = wid; i < 16; i += 4) {
                int r = i * 8 + (lane >> 3);
                glds16(Ab + (size_t)(v0 + r) * CIRB + s * 128 + (((lane & 7) ^ (r & 7)) << 4),
                       As + i * 1024);
            }
        } else {
#pragma unroll
            for (int j = 0; j < 4; ++j) {
                int idx = tid + 256 * j;           // 1024 chunks: v=idx>>3, u=idx&7
                int v = idx >> 3, u = idx & 7;
                short8 raw = *(const short8*)(Ab + (size_t)(v0 + v) * CIRB + s * 128 + u * 16);
                int cb = s * 64 + u * 8 + (AMODE == 2 ? b * KP : 0);
                f4 a0 = *(const f4*)(cfA + cb), a1 = *(const f4*)(cfA + cb + 4);
                f4 d0 = *(const f4*)(cfB + cb), d1 = *(const f4*)(cfB + cb + 4);
                short8 hh;
#pragma unroll
                for (int e = 0; e < 4; ++e) {
                    float t0 = fmaf(a0[e], bu2f((unsigned short)raw[e]),     d0[e]);
                    float t1 = fmaf(a1[e], bu2f((unsigned short)raw[e + 4]), d1[e]);
                    t0 = fmaxf(t0, 0.2f * t0);     // leakyrelu
                    t1 = fmaxf(t1, 0.2f * t1);
                    hh[e]     = (short)f2bu(t0);
                    hh[e + 4] = (short)f2bu(t1);
                }
                *(short8*)(As + v * 128 + ((u ^ (v & 7)) << 4)) = hh;
            }
        }
        __syncthreads();
        // ---- MFMA
#pragma unroll
        for (int ks = 0; ks < 2; ++ks) {
            int kg = ks * 4 + lhi;
            short8 av[2];
#pragma unroll
            for (int mf = 0; mf < 2; ++mf) {
                int v = wid * 32 + mf * 16 + l16;
                av[mf] = *(const short8*)(As + v * 128 + ((kg ^ (v & 7)) << 4));
            }
#pragma unroll
            for (int nf = 0; nf < NF; ++nf) {
                int o = nf * 16 + l16;
                short8 bv = *(const short8*)(Bs + o * 128 + ((kg ^ (o & 7)) << 4));
                acc[0][nf] = __builtin_amdgcn_mfma_f32_16x16x32_bf16(av[0], bv, acc[0][nf], 0, 0, 0);
                acc[1][nf] = __builtin_amdgcn_mfma_f32_16x16x32_bf16(av[1], bv, acc[1][nf], 0, 0, 0);
            }
        }
        __syncthreads();
    }

    // ---- store C (D frag: col = lane&15, row = (lane>>4)*4 + reg)
#pragma unroll
    for (int mf = 0; mf < 2; ++mf) {
        int vb = v0 + wid * 32 + mf * 16 + lhi * 4;
#pragma unroll
        for (int nf = 0; nf < NF; ++nf) {
            int n = n0g + nf * 16 + l16;
#pragma unroll
            for (int r = 0; r < 4; ++r) {
                bf16 o; *(unsigned short*)&o = f2bu(acc[mf][nf][r]);
                Y[(size_t)(vb + r) * CO + n] = o;
            }
        }
    }
    // ---- stats: per-channel sum / sumsq
    float* ps = (float*)smem;      // [4 waves][2][BN], safe: barrier done above
#pragma unroll
    for (int nf = 0; nf < NF; ++nf) {
        float sm = 0.f, sq = 0.f;
#pragma unroll
        for (int mf = 0; mf < 2; ++mf)
#pragma unroll
            for (int r = 0; r < 4; ++r) {
                float v = acc[mf][nf][r];
                sm += v; sq += v * v;
            }
        sm += __shfl_xor(sm, 16); sq += __shfl_xor(sq, 16);
        sm += __shfl_xor(sm, 32); sq += __shfl_xor(sq, 32);
        if (lane < 16) {
            ps[(wid * 2 + 0) * BN + nf * 16 + lane] = sm;
            ps[(wid * 2 + 1) * BN + nf * 16 + lane] = sq;
        }
    }
    __syncthreads();
    if (tid < BN) {
        float sm = ps[0 * BN + tid] + ps[2 * BN + tid] + ps[4 * BN + tid] + ps[6 * BN + tid];
        float sq = ps[1 * BN + tid] + ps[3 * BN + tid] + ps[5 * BN + tid] + ps[7 * BN + tid];
        int slot = PERB ? (b * 32 + (gm & 31)) : (gm & 63);
        float* pb = part + (size_t)(gy * 64 + slot) * 2 * BN;
        atomicAdd(&pb[tid], sm);
        atomicAdd(&pb[BN + tid], sq);
    }
}

// ---------------------------------------------------------------------------
// partial sums -> affine coefs  A = g*rsqrt(var+eps), B = be - m*A
// ---------------------------------------------------------------------------
__global__ void finalize_k(const float* __restrict__ part, float* __restrict__ cf,
                           const float* __restrict__ g, const float* __restrict__ be,
                           int nStats, int CO, int BN, int perB, float invN)
{
    int s = blockIdx.x * 64 + threadIdx.x;
    if (s >= nStats) return;
    int ch = perB ? (s % CO) : s;
    int bb = perB ? (s / CO) : 0;
    int gy = ch / BN, c = ch - gy * BN;
    int j0 = perB ? bb * 32 : 0, cnt = perB ? 32 : 64;
    float sm = 0.f, sq = 0.f;
    for (int j = 0; j < cnt; ++j) {
        const float* pb = part + (size_t)(gy * 64 + j0 + j) * 2 * BN;
        sm += pb[c]; sq += pb[BN + c];
    }
    float m = sm * invN;
    float var = fmaf(-m, m, sq * invN);
    float A = g[ch] * rsqrtf(var + 1e-5f);
    cf[s] = A;
    cf[1024 + s] = fmaf(-m, A, be[ch]);
}

// ---------------------------------------------------------------------------
// weight prep: f32 [CO][CI] -> bf16 [CO][KP], K zero-padded
// ---------------------------------------------------------------------------
__global__ void wprep_k(const float* __restrict__ w0, const float* __restrict__ w1,
                        const float* __restrict__ w2, const float* __restrict__ w3,
                        const float* __restrict__ w4, bf16* __restrict__ Wb)
{
    int i = blockIdx.x * 256 + threadIdx.x;     // < 153600
    const float* src; int r, KP, CI, off;
    if (i < 12288)       { src = w0; r = i;          KP = 128; CI = 96;  off = 0; }
    else if (i < 49152)  { src = w1; r = i - 12288;  KP = 192; CI = 192; off = 12288; }
    else if (i < 67584)  { src = w2; r = i - 49152;  KP = 192; CI = 192; off = 49152; }
    else if (i < 116736) { src = w3; r = i - 67584;  KP = 128; CI = 96;  off = 67584; }
    else                 { src = w4; r = i - 116736; KP = 384; CI = 384; off = 116736; }
    int o = r / KP, k = r - o * KP;
    float v = (k < CI) ? src[o * CI + k] : 0.f;
    bf16 h; *(unsigned short*)&h = f2bu(v);
    Wb[off + r] = h;
}

// ---------------------------------------------------------------------------
// tin: x f32 [b][c][s] -> xT bf16 [v][96] via LDS transpose, 128 voxels/block
// ---------------------------------------------------------------------------
__global__ __launch_bounds__(256)
void tin_k(const float* __restrict__ x, char* __restrict__ xT)
{
    __shared__ float ldsT[128 * 97];
    const int gm = blockIdx.x, b = gm >> 10, s0 = (gm & 1023) * 128;
    const int t = threadIdx.x;
#pragma unroll
    for (int i = 0; i < 12; ++i) {
        int idx = t + 256 * i;                 // (c, s4)
        int c = idx >> 5, s4 = idx & 31;
        f4 r = *(const f4*)(x + ((size_t)(b * 96 + c) << 17) + s0 + s4 * 4);
#pragma unroll
        for (int j = 0; j < 4; ++j) ldsT[(s4 * 4 + j) * 97 + c] = r[j];
    }
    __syncthreads();
#pragma unroll
    for (int i = 0; i < 6; ++i) {
        int idx = t + 256 * i;                 // (row, chunk)
        int r = idx / 12, uc = idx % 12, cb = uc * 8;
        short8 o;
#pragma unroll
        for (int e = 0; e < 8; ++e) o[e] = (short)f2bu(ldsT[r * 97 + cb + e]);
        *(short8*)(xT + (size_t)(b * Sq + s0 + r) * 192 + uc * 16) = o;
    }
}

// ---------------------------------------------------------------------------
// MR pass 1a: dmin[b][h][w][dpar][c] = min over d-residue-class of h1
// grid (whalf, h, b), 256 thr, slots (w,uc) = t and t+256 (<384)
// ---------------------------------------------------------------------------
__global__ __launch_bounds__(256)
void mr_dmin_k(const char* __restrict__ y1, const float* __restrict__ cfA,
               const float* __restrict__ cfB, char* __restrict__ dmin)
{
    const int w0 = blockIdx.x * 32, h = blockIdx.y, b = blockIdx.z;
    const int t = threadIdx.x;
    const int nsl = (t < 128) ? 2 : 1;
    float mn[2][2][8];
    f4 cA[2][2], cB[2][2];
#pragma unroll
    for (int sl = 0; sl < 2; ++sl) {
        int id = t + sl * 256; if (sl >= nsl) break;
        int cb = (id % 12) * 8;
        cA[sl][0] = *(const f4*)(cfA + cb); cA[sl][1] = *(const f4*)(cfA + cb + 4);
        cB[sl][0] = *(const f4*)(cfB + cb); cB[sl][1] = *(const f4*)(cfB + cb + 4);
#pragma unroll
        for (int p = 0; p < 2; ++p)
#pragma unroll
            for (int e = 0; e < 8; ++e) mn[sl][p][e] = 1e30f;
    }
    for (int d = 0; d < 32; ++d) {
        int p = d & 1;
        for (int sl = 0; sl < nsl; ++sl) {
            int id = t + sl * 256;
            int w = id / 12, uc = id % 12;
            short8 raw = *(const short8*)(y1 + (size_t)(b * Sq + d * 4096 + h * 64 + w0 + w) * 192 + uc * 16);
#pragma unroll
            for (int e = 0; e < 4; ++e) {
                mn[sl][p][e]     = fminf(mn[sl][p][e],     fmaf(cA[sl][0][e], bu2f((unsigned short)raw[e]),     cB[sl][0][e]));
                mn[sl][p][e + 4] = fminf(mn[sl][p][e + 4], fmaf(cA[sl][1][e], bu2f((unsigned short)raw[e + 4]), cB[sl][1][e]));
            }
        }
    }
    for (int sl = 0; sl < nsl; ++sl) {
        int id = t + sl * 256;
        int w = id / 12, uc = id % 12;
#pragma unroll
        for (int p = 0; p < 2; ++p) {
            short8 o;
#pragma unroll
            for (int e = 0; e < 8; ++e) o[e] = (short)f2bu(mn[sl][p][e]);
            *(short8*)(dmin + ((size_t)((b * 64 + h) * 64 + w0 + w) * 2 + p) * 192 + uc * 16) = o;
        }
    }
}

// ---------------------------------------------------------------------------
// MR pass 1b: hmin[b][d][w][hpar][c], grid (whalf, d, b)
// ---------------------------------------------------------------------------
__global__ __launch_bounds__(256)
void mr_hmin_k(const char* __restrict__ y1, const float* __restrict__ cfA,
               const float* __restrict__ cfB, char* __restrict__ hmin)
{
    const int w0 = blockIdx.x * 32, d = blockIdx.y, b = blockIdx.z;
    const int t = threadIdx.x;
    const int nsl = (t < 128) ? 2 : 1;
    float mn[2][2][8];
    f4 cA[2][2], cB[2][2];
#pragma unroll
    for (int sl = 0; sl < 2; ++sl) {
        int id = t + sl * 256; if (sl >= nsl) break;
        int cb = (id % 12) * 8;
        cA[sl][0] = *(const f4*)(cfA + cb); cA[sl][1] = *(const f4*)(cfA + cb + 4);
        cB[sl][0] = *(const f4*)(cfB + cb); cB[sl][1] = *(const f4*)(cfB + cb + 4);
#pragma unroll
        for (int p = 0; p < 2; ++p)
#pragma unroll
            for (int e = 0; e < 8; ++e) mn[sl][p][e] = 1e30f;
    }
    for (int h = 0; h < 64; ++h) {
        int p = h & 1;
        for (int sl = 0; sl < nsl; ++sl) {
            int id = t + sl * 256;
            int w = id / 12, uc = id % 12;
            short8 raw = *(const short8*)(y1 + (size_t)(b * Sq + d * 4096 + h * 64 + w0 + w) * 192 + uc * 16);
#pragma unroll
            for (int e = 0; e < 4; ++e) {
                mn[sl][p][e]     = fminf(mn[sl][p][e],     fmaf(cA[sl][0][e], bu2f((unsigned short)raw[e]),     cB[sl][0][e]));
                mn[sl][p][e + 4] = fminf(mn[sl][p][e + 4], fmaf(cA[sl][1][e], bu2f((unsigned short)raw[e + 4]), cB[sl][1][e]));
            }
        }
    }
    for (int sl = 0; sl < nsl; ++sl) {
        int id = t + sl * 256;
        int w = id / 12, uc = id % 12;
#pragma unroll
        for (int p = 0; p < 2; ++p) {
            short8 o;
#pragma unroll
            for (int e = 0; e < 8; ++e) o[e] = (short)f2bu(mn[sl][p][e]);
            *(short8*)(hmin + ((size_t)((b * 32 + d) * 64 + w0 + w) * 2 + p) * 192 + uc * 16) = o;
        }
    }
}

// ---------------------------------------------------------------------------
// MR pass 2: per (b,d,hq): wmin on the fly; hx = [h1 ; h1 - min3]  [v][192]
// ---------------------------------------------------------------------------
__global__ __launch_bounds__(256)
void mr_p2_k(const char* __restrict__ y1, const float* __restrict__ cfA,
             const float* __restrict__ cfB, const char* __restrict__ dmin,
             const char* __restrict__ hmin, char* __restrict__ hx)
{
    __shared__ __align__(16) char rowb[64 * 96 * 2];        // h1 row, bf16
    __shared__ __align__(16) char hlds[64 * 2 * 96 * 2];    // hmin slab for this d
    __shared__ float wlds[2 * 96];
    const int hq = blockIdx.x, d = blockIdx.y, b = blockIdx.z;
    const int t = threadIdx.x;

    for (int i = t; i < 1536; i += 256)
        *(short8*)(hlds + i * 16) = *(const short8*)(hmin + (size_t)(b * 32 + d) * 24576 + i * 16);

    for (int hh = 0; hh < 16; ++hh) {
        int h = hq * 16 + hh;
        __syncthreads();
        // load row, apply affine -> rowb
        for (int i = t; i < 768; i += 256) {
            int w = i / 12, uc = i % 12, cb = uc * 8;
            f4 a0 = *(const f4*)(cfA + cb), a1 = *(const f4*)(cfA + cb + 4);
            f4 d0 = *(const f4*)(cfB + cb), d1 = *(const f4*)(cfB + cb + 4);
            short8 raw = *(const short8*)(y1 + (size_t)(b * Sq + d * 4096 + h * 64 + w) * 192 + uc * 16);
            short8 hv;
#pragma unroll
            for (int e = 0; e < 4; ++e) {
                hv[e]     = (short)f2bu(fmaf(a0[e], bu2f((unsigned short)raw[e]),     d0[e]));
                hv[e + 4] = (short)f2bu(fmaf(a1[e], bu2f((unsigned short)raw[e + 4]), d1[e]));
            }
            *(short8*)(rowb + i * 16) = hv;
        }
        __syncthreads();
        if (t < 192) {          // wmin per (c, wpar)
            int c = t % 96, wp = t / 96;
            float m = 1e30f;
            for (int w2 = wp; w2 < 64; w2 += 2)
                m = fminf(m, bu2f(*(const unsigned short*)(rowb + (w2 * 96 + c) * 2)));
            wlds[wp * 96 + c] = m;
        }
        __syncthreads();
        for (int i = t; i < 768; i += 256) {
            int w = i / 12, uc = i % 12, cb = uc * 8;
            short8 hv = *(const short8*)(rowb + i * 16);
            short8 dm = *(const short8*)(dmin + ((size_t)((b * 64 + h) * 64 + w) * 2 + (d & 1)) * 192 + uc * 16);
            short8 hm = *(const short8*)(hlds + (w * 2 + (h & 1)) * 192 + uc * 16);
            short8 xo;
#pragma unroll
            for (int e = 0; e < 8; ++e) {
                float hf = bu2f((unsigned short)hv[e]);
                float m = fminf(fminf(bu2f((unsigned short)dm[e]), bu2f((unsigned short)hm[e])),
                                wlds[(w & 1) * 96 + cb + e]);
                xo[e] = (short)f2bu(hf - m);
            }
            size_t vb = (size_t)(b * Sq + d * 4096 + h * 64 + w) * 384;
            *(short8*)(hx + vb + uc * 16) = hv;
            *(short8*)(hx + vb + 192 + uc * 16) = xo;
        }
    }
}

// ---------------------------------------------------------------------------
// ewx2: x2[v][c] = A3*y2 + B3 + x (x transpose-read via LDS)
// ---------------------------------------------------------------------------
__global__ __launch_bounds__(256)
void ewx2_k(const char* __restrict__ y2, const float* __restrict__ cfA,
            const float* __restrict__ cfB, const float* __restrict__ x,
            char* __restrict__ x2)
{
    __shared__ float ldsT[128 * 97];
    const int gm = blockIdx.x, b = gm >> 10, s0 = (gm & 1023) * 128;
    const int t = threadIdx.x;
#pragma unroll
    for (int i = 0; i < 12; ++i) {
        int idx = t + 256 * i;
        int c = idx >> 5, s4 = idx & 31;
        f4 r = *(const f4*)(x + ((size_t)(b * 96 + c) << 17) + s0 + s4 * 4);
#pragma unroll
        for (int j = 0; j < 4; ++j) ldsT[(s4 * 4 + j) * 97 + c] = r[j];
    }
    __syncthreads();
#pragma unroll
    for (int i = 0; i < 6; ++i) {
        int idx = t + 256 * i;
        int r = idx / 12, uc = idx % 12, cb = uc * 8;
        size_t vv = (size_t)(b * Sq + s0 + r);
        short8 yv = *(const short8*)(y2 + vv * 192 + uc * 16);
        f4 a0 = *(const f4*)(cfA + cb), a1 = *(const f4*)(cfA + cb + 4);
        f4 d0 = *(const f4*)(cfB + cb), d1 = *(const f4*)(cfB + cb + 4);
        short8 o;
#pragma unroll
        for (int e = 0; e < 4; ++e) {
            float t0 = fmaf(a0[e], bu2f((unsigned short)yv[e]),     d0[e]) + ldsT[r * 97 + cb + e];
            float t1 = fmaf(a1[e], bu2f((unsigned short)yv[e + 4]), d1[e]) + ldsT[r * 97 + cb + e + 4];
            o[e]     = (short)f2bu(t0);
            o[e + 4] = (short)f2bu(t1);
        }
        *(short8*)(x2 + vv * 192 + uc * 16) = o;
    }
}

// ---------------------------------------------------------------------------
// tout: out f32 [b][c][s] = A5*y4 + B5 + x2   (transpose via LDS)
// ---------------------------------------------------------------------------
__global__ __launch_bounds__(256)
void tout_k(const char* __restrict__ y4, const float* __restrict__ cfA,
            const float* __restrict__ cfB, const char* __restrict__ x2,
            float* __restrict__ outp)
{
    __shared__ float ldsT[128 * 97];
    const int gm = blockIdx.x, b = gm >> 10, s0 = (gm & 1023) * 128;
    const int t = threadIdx.x;
#pragma unroll
    for (int i = 0; i < 6; ++i) {
        int idx = t + 256 * i;
        int r = idx / 12, uc = idx % 12, cb = uc * 8;
        size_t vv = (size_t)(b * Sq + s0 + r);
        short8 yv = *(const short8*)(y4 + vv * 192 + uc * 16);
        short8 xv = *(const short8*)(x2 + vv * 192 + uc * 16);
        f4 a0 = *(const f4*)(cfA + cb), a1 = *(const f4*)(cfA + cb + 4);
        f4 d0 = *(const f4*)(cfB + cb), d1 = *(const f4*)(cfB + cb + 4);
#pragma unroll
        for (int e = 0; e < 4; ++e) {
            ldsT[r * 97 + cb + e]     = fmaf(a0[e], bu2f((unsigned short)yv[e]),     d0[e]) + bu2f((unsigned short)xv[e]);
            ldsT[r * 97 + cb + e + 4] = fmaf(a1[e], bu2f((unsigned short)yv[e + 4]), d1[e]) + bu2f((unsigned short)xv[e + 4]);
        }
    }
    __syncthreads();
#pragma unroll
    for (int i = 0; i < 12; ++i) {
        int idx = t + 256 * i;
        int c = idx >> 5, s4 = idx & 31;
        f4 o;
#pragma unroll
        for (int j = 0; j < 4; ++j) o[j] = ldsT[(s4 * 4 + j) * 97 + c];
        *(f4*)(outp + ((size_t)(b * 96 + c) << 17) + s0 + s4 * 4) = o;
    }
}

// ===========================================================================
extern "C" void kernel_launch(void* const* d_in, const int* in_sizes, int n_in,
                              void* d_out, int out_size, void* d_ws, size_t ws_size,
                              hipStream_t stream)
{
    (void)in_sizes; (void)n_in; (void)out_size; (void)ws_size;

    const float* x      = (const float*)d_in[0];
    const float* w_fc1  = (const float*)d_in[1];
    const float* b_fc1  = (const float*)d_in[2];
    const float* g_bn1  = (const float*)d_in[3];
    const float* be_bn1 = (const float*)d_in[4];
    const float* w_g    = (const float*)d_in[5];
    const float* b_g    = (const float*)d_in[6];
    const float* g_in   = (const float*)d_in[7];
    const float* be_in  = (const float*)d_in[8];
    const float* w_fc2  = (const float*)d_in[9];
    const float* b_fc2  = (const float*)d_in[10];
    const float* g_bn2  = (const float*)d_in[11];
    const float* be_bn2 = (const float*)d_in[12];
    const float* w_f1   = (const float*)d_in[13];
    const float* b_f1   = (const float*)d_in[14];
    const float* g_bnf1 = (const float*)d_in[15];
    const float* be_bnf1= (const float*)d_in[16];
    const float* w_f2   = (const float*)d_in[17];
    const float* b_f2   = (const float*)d_in[18];
    const float* g_bnf2 = (const float*)d_in[19];
    const float* be_bnf2= (const float*)d_in[20];
    float* outp = (float*)d_out;

    char* W = (char*)d_ws;
    // region S0 [0,50.3MB): xT -> (dmin/hmin during MR) -> y2 -> y4
    char* xT   = W;
    char* dmin = W;
    char* hmin = W + 3145728;
    char* y2   = W;
    char* y4   = W;
    // region S1: y1 -> x2
    char* y1 = W + 50331648;
    char* x2 = W + 50331648;
    // region S2/S3: hx, yg ; y3 spans both after they die
    char* hx = W + 100663296;
    char* yg = W + 201326592;
    char* y3 = W + 100663296;
    // misc
    char* M = W + 301989888;
    bf16*  Wb   = (bf16*)M;                    // 307200 B
    float* cf   = (float*)(M + 307200);        // 5 slots x 2048 f32
    float* part = (float*)(M + 348160);        // 5 slots x 49152 f32

    hipMemsetAsync(part, 0, 5 * 196608, stream);

    const float invBN = 1.f / (float)NVq, invIN = 1.f / (float)Sq;
    dim3 blk(256);

    wprep_k<<<600, blk, 0, stream>>>(w_fc1, w_g, w_fc2, w_f1, w_f2, Wb);
    tin_k<<<2048, blk, 0, stream>>>(x, xT);

    // fc1: 96 -> 96
    conv_k<192, 128, 96, 96, 0, false><<<dim3(2048, 1), blk, 0, stream>>>(
        xT, (const char*)Wb, b_fc1, nullptr, nullptr, (bf16*)y1, part);
    finalize_k<<<2, 64, 0, stream>>>(part, cf, g_bn1, be_bn1, 96, 96, 96, 0, invBN);

    // MRConv
    mr_dmin_k<<<dim3(2, 64, 2), blk, 0, stream>>>(y1, cf, cf + 1024, dmin);
    mr_hmin_k<<<dim3(2, 32, 2), blk, 0, stream>>>(y1, cf, cf + 1024, hmin);
    mr_p2_k<<<dim3(4, 32, 2), blk, 0, stream>>>(y1, cf, cf + 1024, dmin, hmin, hx);

    // grapher conv: 192 -> 192, InstanceNorm stats (per b,c)
    conv_k<384, 192, 192, 192, 0, true><<<dim3(2048, 1), blk, 0, stream>>>(
        hx, (const char*)Wb + 24576, b_g, nullptr, nullptr, (bf16*)yg, part + 49152);
    finalize_k<<<6, 64, 0, stream>>>(part + 49152, cf + 2048, g_in, be_in, 384, 192, 192, 1, invIN);

    // fc2: 192 -> 96, loader = lrelu(A2*yg+B2) per (b,c)
    conv_k<384, 192, 96, 96, 2, false><<<dim3(2048, 1), blk, 0, stream>>>(
        yg, (const char*)Wb + 98304, b_fc2, cf + 2048, cf + 2048 + 1024, (bf16*)y2, part + 98304);
    finalize_k<<<2, 64, 0, stream>>>(part + 98304, cf + 4096, g_bn2, be_bn2, 96, 96, 96, 0, invBN);

    ewx2_k<<<2048, blk, 0, stream>>>(y2, cf + 4096, cf + 4096 + 1024, x, x2);

    // f1: 96 -> 384
    conv_k<192, 128, 384, 192, 0, false><<<dim3(2048, 2), blk, 0, stream>>>(
        x2, (const char*)Wb + 135168, b_f1, nullptr, nullptr, (bf16*)y3, part + 147456);
    finalize_k<<<6, 64, 0, stream>>>(part + 147456, cf + 6144, g_bnf1, be_bnf1, 384, 384, 192, 0, invBN);

    // f2: 384 -> 96, loader = lrelu(A4*y3+B4) per c
    conv_k<768, 384, 96, 96, 1, false><<<dim3(2048, 1), blk, 0, stream>>>(
        y3, (const char*)Wb + 233472, b_f2, cf + 6144, cf + 6144 + 1024, (bf16*)y4, part + 196608);
    finalize_k<<<2, 64, 0, stream>>>(part + 196608, cf + 8192, g_bnf2, be_bnf2, 96, 96, 96, 0, invBN);

    tout_k<<<2048, blk, 0, stream>>>(y4, cf + 8192, cf + 8192 + 1024, x2, outp);
}

// Round 3
// 511.309 us; speedup vs baseline: 3.3346x; 1.3156x over previous
//
#include <hip/hip_runtime.h>
#include <hip/hip_bf16.h>

// ============================================================================
// NexToU encoder block, MFMA bf16 version. All activations in [voxel][channel]
// (channel-fast) layout so every 1x1x1-conv GEMM has K-contiguous operands.
//
//  wprep : weights f32 [CO][CI] -> bf16 [CO][KP] (K zero-padded to mult of 64)
//  tin   : x f32 [b][c][s] -> xT bf16 [v][96]         (LDS transpose)
//  conv fc1 (MFMA)  xT -> y1, BN1 partials
//  mr dmin/hmin     y1(+c1 affine) -> partial residue-min fields (LLC-resident)
//  mr p2            y1 -> hx = [h1 ; xj]  [v][192]  (w-min in LDS per row)
//  conv g  (MFMA)   hx -> yg, IN partials (per b,c)
//  conv fc2 (MFMA, loader = lrelu(A2*yg+B2) per (b,c))  -> y2, BN2 partials
//  ewx2  : x2 = A3*y2+B3 + x   (transpose-reads x)     [v][96] bf16
//  conv f1 (MFMA)   x2 -> y3 [v][384], BNf1 partials
//  conv f2 (MFMA, loader = lrelu(A4*y3+B4))            -> y4, BNf2 partials
//  tout  : out = A5*y4+B5 + x2, transposed back to f32 [b][c][s]
// ============================================================================

typedef __hip_bfloat16 bf16;
typedef __attribute__((ext_vector_type(8))) short short8;
typedef __attribute__((ext_vector_type(4))) float f4;

#define DEV static __device__ __forceinline__

constexpr int Sq  = 131072;   // D*H*W
constexpr int NVq = 262144;   // B*S

DEV float bu2f(unsigned short u) { return __uint_as_float(((unsigned)u) << 16); }
DEV unsigned short f2bu(float f) {
    unsigned i = __float_as_uint(f);
    unsigned r = i + 0x7FFFu + ((i >> 16) & 1u);   // RNE (finite inputs only)
    return (unsigned short)(r >> 16);
}
DEV void glds16(const void* g, void* l) {
    __builtin_amdgcn_global_load_lds(
        (const __attribute__((address_space(1))) unsigned*)g,
        (__attribute__((address_space(3))) unsigned*)l, 16, 0, 0);
}

// ---------------------------------------------------------------------------
// MFMA conv: Y[v][n] = sum_k A[v][k] * W[n][k] + bias[n], with fused stats.
// BM=128 (4 waves x 32 rows), BN = 96 or 192 (gy splits CO), BK=64.
// AMODE: 0 plain (global_load_lds), 1 per-c affine+lrelu (reg-staged),
//        2 per-(b,c) affine+lrelu (reg-staged).
// LDS layout: A [128 rows][8 x 16B chunks], chunk u of row v stored at unit
// u^(v&7)  -> conflict-free ds_read_b128 fragments. Same for B.
// ---------------------------------------------------------------------------
template<int CIRB, int KP, int CO, int BN, int AMODE, bool PERB>
__global__ __launch_bounds__(256)
void conv_k(const char* __restrict__ Ab, const char* __restrict__ Wb,
            const float* __restrict__ bias,
            const float* __restrict__ cfA, const float* __restrict__ cfB,
            bf16* __restrict__ Y, float* __restrict__ part)
{
    constexpr int NSTEP = KP / 64;
    constexpr int NF = BN / 16;
    constexpr int BI = BN / 8;
    __shared__ __align__(16) char smem[16384 + BN * 128];
    char* As = smem;
    char* Bs = smem + 16384;

    const int tid = threadIdx.x;
    const int lane = tid & 63, wid = tid >> 6, l16 = lane & 15, lhi = lane >> 4;
    const int gm = blockIdx.x, gy = blockIdx.y;
    const int v0 = gm * 128;
    const int b = gm >> 10;          // 1024 M-blocks per batch sample
    const int n0g = gy * BN;

    f4 acc[2][NF];
#pragma unroll
    for (int nf = 0; nf < NF; ++nf) {
        float bb = bias[n0g + nf * 16 + l16];
        f4 t = {bb, bb, bb, bb};
        acc[0][nf] = t; acc[1][nf] = t;
    }

    for (int s = 0; s < NSTEP; ++s) {
        // ---- stage B tile (weights, bf16-padded, plain)
        for (int i = wid; i < BI; i += 4) {
            int o = i * 8 + (lane >> 3);
            glds16(Wb + (size_t)(n0g + o) * (KP * 2) + s * 128 + (((lane & 7) ^ (o & 7)) << 4),
                   Bs + i * 1024);
        }
        // ---- stage A tile
        if constexpr (AMODE == 0) {
            for (int i = wid; i < 16; i += 4) {
                int r = i * 8 + (lane >> 3);
                glds16(Ab + (size_t)(v0 + r) * CIRB + s * 128 + (((lane & 7) ^ (r & 7)) << 4),
                       As + i * 1024);
            }
        } else {
#pragma unroll
            for (int j = 0; j < 4; ++j) {
                int idx = tid + 256 * j;           // 1024 chunks: v=idx>>3, u=idx&7
                int v = idx >> 3, u = idx & 7;
                short8 raw = *(const short8*)(Ab + (size_t)(v0 + v) * CIRB + s * 128 + u * 16);
                int cb = s * 64 + u * 8 + (AMODE == 2 ? b * KP : 0);
                f4 a0 = *(const f4*)(cfA + cb), a1 = *(const f4*)(cfA + cb + 4);
                f4 d0 = *(const f4*)(cfB + cb), d1 = *(const f4*)(cfB + cb + 4);
                short8 hh;
#pragma unroll
                for (int e = 0; e < 4; ++e) {
                    float t0 = fmaf(a0[e], bu2f((unsigned short)raw[e]),     d0[e]);
                    float t1 = fmaf(a1[e], bu2f((unsigned short)raw[e + 4]), d1[e]);
                    t0 = fmaxf(t0, 0.2f * t0);     // leakyrelu
                    t1 = fmaxf(t1, 0.2f * t1);
                    hh[e]     = (short)f2bu(t0);
                    hh[e + 4] = (short)f2bu(t1);
                }
                *(short8*)(As + v * 128 + ((u ^ (v & 7)) << 4)) = hh;
            }
        }
        __syncthreads();
        // ---- MFMA
#pragma unroll
        for (int ks = 0; ks < 2; ++ks) {
            int kg = ks * 4 + lhi;
            short8 av[2];
#pragma unroll
            for (int mf = 0; mf < 2; ++mf) {
                int v = wid * 32 + mf * 16 + l16;
                av[mf] = *(const short8*)(As + v * 128 + ((kg ^ (v & 7)) << 4));
            }
#pragma unroll
            for (int nf = 0; nf < NF; ++nf) {
                int o = nf * 16 + l16;
                short8 bv = *(const short8*)(Bs + o * 128 + ((kg ^ (o & 7)) << 4));
                acc[0][nf] = __builtin_amdgcn_mfma_f32_16x16x32_bf16(av[0], bv, acc[0][nf], 0, 0, 0);
                acc[1][nf] = __builtin_amdgcn_mfma_f32_16x16x32_bf16(av[1], bv, acc[1][nf], 0, 0, 0);
            }
        }
        __syncthreads();
    }

    // ---- store C (D frag: col = lane&15, row = (lane>>4)*4 + reg)
#pragma unroll
    for (int mf = 0; mf < 2; ++mf) {
        int vb = v0 + wid * 32 + mf * 16 + lhi * 4;
#pragma unroll
        for (int nf = 0; nf < NF; ++nf) {
            int n = n0g + nf * 16 + l16;
#pragma unroll
            for (int r = 0; r < 4; ++r) {
                bf16 o; *(unsigned short*)&o = f2bu(acc[mf][nf][r]);
                Y[(size_t)(vb + r) * CO + n] = o;
            }
        }
    }
    // ---- stats: per-channel sum / sumsq
    float* ps = (float*)smem;      // [4 waves][2][BN], safe: barrier done above
#pragma unroll
    for (int nf = 0; nf < NF; ++nf) {
        float sm = 0.f, sq = 0.f;
#pragma unroll
        for (int mf = 0; mf < 2; ++mf)
#pragma unroll
            for (int r = 0; r < 4; ++r) {
                float v = acc[mf][nf][r];
                sm += v; sq += v * v;
            }
        sm += __shfl_xor(sm, 16); sq += __shfl_xor(sq, 16);
        sm += __shfl_xor(sm, 32); sq += __shfl_xor(sq, 32);
        if (lane < 16) {
            ps[(wid * 2 + 0) * BN + nf * 16 + lane] = sm;
            ps[(wid * 2 + 1) * BN + nf * 16 + lane] = sq;
        }
    }
    __syncthreads();
    if (tid < BN) {
        float sm = ps[0 * BN + tid] + ps[2 * BN + tid] + ps[4 * BN + tid] + ps[6 * BN + tid];
        float sq = ps[1 * BN + tid] + ps[3 * BN + tid] + ps[5 * BN + tid] + ps[7 * BN + tid];
        int slot = PERB ? (b * 32 + (gm & 31)) : (gm & 63);
        float* pb = part + (size_t)(gy * 64 + slot) * 2 * BN;
        atomicAdd(&pb[tid], sm);
        atomicAdd(&pb[BN + tid], sq);
    }
}

// ---------------------------------------------------------------------------
// partial sums -> affine coefs  A = g*rsqrt(var+eps), B = be - m*A
// ---------------------------------------------------------------------------
__global__ void finalize_k(const float* __restrict__ part, float* __restrict__ cf,
                           const float* __restrict__ g, const float* __restrict__ be,
                           int nStats, int CO, int BN, int perB, float invN)
{
    int s = blockIdx.x * 64 + threadIdx.x;
    if (s >= nStats) return;
    int ch = perB ? (s % CO) : s;
    int bb = perB ? (s / CO) : 0;
    int gy = ch / BN, c = ch - gy * BN;
    int j0 = perB ? bb * 32 : 0, cnt = perB ? 32 : 64;
    float sm = 0.f, sq = 0.f;
    for (int j = 0; j < cnt; ++j) {
        const float* pb = part + (size_t)(gy * 64 + j0 + j) * 2 * BN;
        sm += pb[c]; sq += pb[BN + c];
    }
    float m = sm * invN;
    float var = fmaf(-m, m, sq * invN);
    float A = g[ch] * rsqrtf(var + 1e-5f);
    cf[s] = A;
    cf[1024 + s] = fmaf(-m, A, be[ch]);
}

// ---------------------------------------------------------------------------
// weight prep: f32 [CO][CI] -> bf16 [CO][KP], K zero-padded
// ---------------------------------------------------------------------------
__global__ void wprep_k(const float* __restrict__ w0, const float* __restrict__ w1,
                        const float* __restrict__ w2, const float* __restrict__ w3,
                        const float* __restrict__ w4, bf16* __restrict__ Wb)
{
    int i = blockIdx.x * 256 + threadIdx.x;     // < 153600
    const float* src; int r, KP, CI, off;
    if (i < 12288)       { src = w0; r = i;          KP = 128; CI = 96;  off = 0; }
    else if (i < 49152)  { src = w1; r = i - 12288;  KP = 192; CI = 192; off = 12288; }
    else if (i < 67584)  { src = w2; r = i - 49152;  KP = 192; CI = 192; off = 49152; }
    else if (i < 116736) { src = w3; r = i - 67584;  KP = 128; CI = 96;  off = 67584; }
    else                 { src = w4; r = i - 116736; KP = 384; CI = 384; off = 116736; }
    int o = r / KP, k = r - o * KP;
    float v = (k < CI) ? src[o * CI + k] : 0.f;
    bf16 h; *(unsigned short*)&h = f2bu(v);
    Wb[off + r] = h;
}

// ---------------------------------------------------------------------------
// tin: x f32 [b][c][s] -> xT bf16 [v][96] via LDS transpose, 128 voxels/block
// ---------------------------------------------------------------------------
__global__ __launch_bounds__(256)
void tin_k(const float* __restrict__ x, char* __restrict__ xT)
{
    __shared__ float ldsT[128 * 97];
    const int gm = blockIdx.x, b = gm >> 10, s0 = (gm & 1023) * 128;
    const int t = threadIdx.x;
#pragma unroll
    for (int i = 0; i < 12; ++i) {
        int idx = t + 256 * i;                 // (c, s4)
        int c = idx >> 5, s4 = idx & 31;
        f4 r = *(const f4*)(x + ((size_t)(b * 96 + c) << 17) + s0 + s4 * 4);
#pragma unroll
        for (int j = 0; j < 4; ++j) ldsT[(s4 * 4 + j) * 97 + c] = r[j];
    }
    __syncthreads();
#pragma unroll
    for (int i = 0; i < 6; ++i) {
        int idx = t + 256 * i;                 // (row, chunk)
        int r = idx / 12, uc = idx % 12, cb = uc * 8;
        short8 o;
#pragma unroll
        for (int e = 0; e < 8; ++e) o[e] = (short)f2bu(ldsT[r * 97 + cb + e]);
        *(short8*)(xT + (size_t)(b * Sq + s0 + r) * 192 + uc * 16) = o;
    }
}

// ---------------------------------------------------------------------------
// MR pass 1a: dminp[b][h][w][dh][p][c] = min over d in half dh, parity p, of h1
// grid (wq4*dh2=8, h=64, b=2), 192 threads: thread = (w = t/12, uc = t%12)
// ---------------------------------------------------------------------------
__global__ __launch_bounds__(192)
void mr_dmin_k(const char* __restrict__ y1, const float* __restrict__ cfA,
               const float* __restrict__ cfB, char* __restrict__ dminp)
{
    const int wq = blockIdx.x >> 1, dh = blockIdx.x & 1;
    const int h = blockIdx.y, b = blockIdx.z;
    const int t = threadIdx.x;
    const int w = wq * 16 + t / 12, uc = t % 12, cb = uc * 8;
    f4 a0 = *(const f4*)(cfA + cb), a1 = *(const f4*)(cfA + cb + 4);
    f4 c0 = *(const f4*)(cfB + cb), c1 = *(const f4*)(cfB + cb + 4);
    const char* base = y1 + (size_t)(b * Sq + dh * 16 * 4096 + h * 64 + w) * 192 + uc * 16;
    float mn[2][8];
#pragma unroll
    for (int p = 0; p < 2; ++p)
#pragma unroll
        for (int e = 0; e < 8; ++e) mn[p][e] = 1e30f;
#pragma unroll 4
    for (int i = 0; i < 16; ++i) {
        short8 raw = *(const short8*)(base + (size_t)i * (4096 * 192));
        int p = i & 1;
#pragma unroll
        for (int e = 0; e < 4; ++e) {
            mn[p][e]     = fminf(mn[p][e],     fmaf(a0[e], bu2f((unsigned short)raw[e]),     c0[e]));
            mn[p][e + 4] = fminf(mn[p][e + 4], fmaf(a1[e], bu2f((unsigned short)raw[e + 4]), c1[e]));
        }
    }
#pragma unroll
    for (int p = 0; p < 2; ++p) {
        short8 o;
#pragma unroll
        for (int e = 0; e < 8; ++e) o[e] = (short)f2bu(mn[p][e]);
        *(short8*)(dminp + (size_t)((((b * 64 + h) * 64 + w) * 2 + dh) * 2 + p) * 192 + uc * 16) = o;
    }
}

// ---------------------------------------------------------------------------
// MR pass 1b: hminp[b][d][w][hq][p][c] = min over h in quarter hq, parity p
// grid (wq4*hq4=16, d=32, b=2), 192 threads
// ---------------------------------------------------------------------------
__global__ __launch_bounds__(192)
void mr_hmin_k(const char* __restrict__ y1, const float* __restrict__ cfA,
               const float* __restrict__ cfB, char* __restrict__ hminp)
{
    const int wq = blockIdx.x >> 2, hq = blockIdx.x & 3;
    const int d = blockIdx.y, b = blockIdx.z;
    const int t = threadIdx.x;
    const int w = wq * 16 + t / 12, uc = t % 12, cb = uc * 8;
    f4 a0 = *(const f4*)(cfA + cb), a1 = *(const f4*)(cfA + cb + 4);
    f4 c0 = *(const f4*)(cfB + cb), c1 = *(const f4*)(cfB + cb + 4);
    const char* base = y1 + (size_t)(b * Sq + d * 4096 + hq * 16 * 64 + w) * 192 + uc * 16;
    float mn[2][8];
#pragma unroll
    for (int p = 0; p < 2; ++p)
#pragma unroll
        for (int e = 0; e < 8; ++e) mn[p][e] = 1e30f;
#pragma unroll 4
    for (int i = 0; i < 16; ++i) {
        short8 raw = *(const short8*)(base + (size_t)i * (64 * 192));
        int p = i & 1;
#pragma unroll
        for (int e = 0; e < 4; ++e) {
            mn[p][e]     = fminf(mn[p][e],     fmaf(a0[e], bu2f((unsigned short)raw[e]),     c0[e]));
            mn[p][e + 4] = fminf(mn[p][e + 4], fmaf(a1[e], bu2f((unsigned short)raw[e + 4]), c1[e]));
        }
    }
#pragma unroll
    for (int p = 0; p < 2; ++p) {
        short8 o;
#pragma unroll
        for (int e = 0; e < 8; ++e) o[e] = (short)f2bu(mn[p][e]);
        *(short8*)(hminp + (size_t)((((b * 32 + d) * 64 + w) * 4 + hq) * 2 + p) * 192 + uc * 16) = o;
    }
}

// ---------------------------------------------------------------------------
// MR pass 2: one block per row (b,d,h). Row -> LDS, w-min in LDS, then
// hx = [h1 ; h1 - min(dminp x2, hminp x4, wmin)]. grid (h=64, d=32, b=2).
// ---------------------------------------------------------------------------
__global__ __launch_bounds__(256)
void mr_p2_k(const char* __restrict__ y1, const float* __restrict__ cfA,
             const float* __restrict__ cfB, const char* __restrict__ dminp,
             const char* __restrict__ hminp, char* __restrict__ hx)
{
    __shared__ __align__(16) char rowb[64 * 96 * 2];   // h1 row, bf16 [w][c]
    __shared__ float wlds[2 * 96];                      // [wpar][c]
    const int h = blockIdx.x, d = blockIdx.y, b = blockIdx.z;
    const int t = threadIdx.x;

    short8 hv[3];
#pragma unroll
    for (int j = 0; j < 3; ++j) {
        int slot = t + 256 * j;
        int w = slot / 12, uc = slot % 12, cb = uc * 8;
        f4 a0 = *(const f4*)(cfA + cb), a1 = *(const f4*)(cfA + cb + 4);
        f4 c0 = *(const f4*)(cfB + cb), c1 = *(const f4*)(cfB + cb + 4);
        short8 raw = *(const short8*)(y1 + (size_t)(b * Sq + d * 4096 + h * 64 + w) * 192 + uc * 16);
        short8 o;
#pragma unroll
        for (int e = 0; e < 4; ++e) {
            o[e]     = (short)f2bu(fmaf(a0[e], bu2f((unsigned short)raw[e]),     c0[e]));
            o[e + 4] = (short)f2bu(fmaf(a1[e], bu2f((unsigned short)raw[e + 4]), c1[e]));
        }
        hv[j] = o;
        *(short8*)(rowb + slot * 16) = o;
    }
    __syncthreads();
    if (t < 192) {
        int p = t / 96, c = t % 96;
        float m = 1e30f;
        for (int w2 = p; w2 < 64; w2 += 2)
            m = fminf(m, bu2f(*(const unsigned short*)(rowb + (w2 * 96 + c) * 2)));
        wlds[t] = m;                                   // t = p*96 + c
    }
    __syncthreads();
#pragma unroll
    for (int j = 0; j < 3; ++j) {
        int slot = t + 256 * j;
        int w = slot / 12, uc = slot % 12, cb = uc * 8;
        const char* dp = dminp + (size_t)((((b * 64 + h) * 64 + w) * 2) * 2 + (d & 1)) * 192 + uc * 16;
        short8 dm0 = *(const short8*)(dp);
        short8 dm1 = *(const short8*)(dp + 384);
        const char* hp = hminp + (size_t)((((b * 32 + d) * 64 + w) * 4) * 2 + (h & 1)) * 192 + uc * 16;
        short8 hm0 = *(const short8*)(hp);
        short8 hm1 = *(const short8*)(hp + 384);
        short8 hm2 = *(const short8*)(hp + 768);
        short8 hm3 = *(const short8*)(hp + 1152);
        short8 xo;
#pragma unroll
        for (int e = 0; e < 8; ++e) {
            float m = fminf(
                fminf(bu2f((unsigned short)dm0[e]), bu2f((unsigned short)dm1[e])),
                fminf(fminf(fminf(bu2f((unsigned short)hm0[e]), bu2f((unsigned short)hm1[e])),
                            fminf(bu2f((unsigned short)hm2[e]), bu2f((unsigned short)hm3[e]))),
                      wlds[(w & 1) * 96 + cb + e]));
            xo[e] = (short)f2bu(bu2f((unsigned short)hv[j][e]) - m);
        }
        size_t vb = (size_t)(b * Sq + d * 4096 + h * 64 + w) * 384;
        *(short8*)(hx + vb + uc * 16) = hv[j];
        *(short8*)(hx + vb + 192 + uc * 16) = xo;
    }
}

// ---------------------------------------------------------------------------
// ewx2: x2[v][c] = A3*y2 + B3 + x (x transpose-read via LDS)
// ---------------------------------------------------------------------------
__global__ __launch_bounds__(256)
void ewx2_k(const char* __restrict__ y2, const float* __restrict__ cfA,
            const float* __restrict__ cfB, const float* __restrict__ x,
            char* __restrict__ x2)
{
    __shared__ float ldsT[128 * 97];
    const int gm = blockIdx.x, b = gm >> 10, s0 = (gm & 1023) * 128;
    const int t = threadIdx.x;
#pragma unroll
    for (int i = 0; i < 12; ++i) {
        int idx = t + 256 * i;
        int c = idx >> 5, s4 = idx & 31;
        f4 r = *(const f4*)(x + ((size_t)(b * 96 + c) << 17) + s0 + s4 * 4);
#pragma unroll
        for (int j = 0; j < 4; ++j) ldsT[(s4 * 4 + j) * 97 + c] = r[j];
    }
    __syncthreads();
#pragma unroll
    for (int i = 0; i < 6; ++i) {
        int idx = t + 256 * i;
        int r = idx / 12, uc = idx % 12, cb = uc * 8;
        size_t vv = (size_t)(b * Sq + s0 + r);
        short8 yv = *(const short8*)(y2 + vv * 192 + uc * 16);
        f4 a0 = *(const f4*)(cfA + cb), a1 = *(const f4*)(cfA + cb + 4);
        f4 d0 = *(const f4*)(cfB + cb), d1 = *(const f4*)(cfB + cb + 4);
        short8 o;
#pragma unroll
        for (int e = 0; e < 4; ++e) {
            float t0 = fmaf(a0[e], bu2f((unsigned short)yv[e]),     d0[e]) + ldsT[r * 97 + cb + e];
            float t1 = fmaf(a1[e], bu2f((unsigned short)yv[e + 4]), d1[e]) + ldsT[r * 97 + cb + e + 4];
            o[e]     = (short)f2bu(t0);
            o[e + 4] = (short)f2bu(t1);
        }
        *(short8*)(x2 + vv * 192 + uc * 16) = o;
    }
}

// ---------------------------------------------------------------------------
// tout: out f32 [b][c][s] = A5*y4 + B5 + x2   (transpose via LDS)
// ---------------------------------------------------------------------------
__global__ __launch_bounds__(256)
void tout_k(const char* __restrict__ y4, const float* __restrict__ cfA,
            const float* __restrict__ cfB, const char* __restrict__ x2,
            float* __restrict__ outp)
{
    __shared__ float ldsT[128 * 97];
    const int gm = blockIdx.x, b = gm >> 10, s0 = (gm & 1023) * 128;
    const int t = threadIdx.x;
#pragma unroll
    for (int i = 0; i < 6; ++i) {
        int idx = t + 256 * i;
        int r = idx / 12, uc = idx % 12, cb = uc * 8;
        size_t vv = (size_t)(b * Sq + s0 + r);
        short8 yv = *(const short8*)(y4 + vv * 192 + uc * 16);
        short8 xv = *(const short8*)(x2 + vv * 192 + uc * 16);
        f4 a0 = *(const f4*)(cfA + cb), a1 = *(const f4*)(cfA + cb + 4);
        f4 d0 = *(const f4*)(cfB + cb), d1 = *(const f4*)(cfB + cb + 4);
#pragma unroll
        for (int e = 0; e < 4; ++e) {
            ldsT[r * 97 + cb + e]     = fmaf(a0[e], bu2f((unsigned short)yv[e]),     d0[e]) + bu2f((unsigned short)xv[e]);
            ldsT[r * 97 + cb + e + 4] = fmaf(a1[e], bu2f((unsigned short)yv[e + 4]), d1[e]) + bu2f((unsigned short)xv[e + 4]);
        }
    }
    __syncthreads();
#pragma unroll
    for (int i = 0; i < 12; ++i) {
        int idx = t + 256 * i;
        int c = idx >> 5, s4 = idx & 31;
        f4 o;
#pragma unroll
        for (int j = 0; j < 4; ++j) o[j] = ldsT[(s4 * 4 + j) * 97 + c];
        *(f4*)(outp + ((size_t)(b * 96 + c) << 17) + s0 + s4 * 4) = o;
    }
}

// ===========================================================================
extern "C" void kernel_launch(void* const* d_in, const int* in_sizes, int n_in,
                              void* d_out, int out_size, void* d_ws, size_t ws_size,
                              hipStream_t stream)
{
    (void)in_sizes; (void)n_in; (void)out_size; (void)ws_size;

    const float* x      = (const float*)d_in[0];
    const float* w_fc1  = (const float*)d_in[1];
    const float* b_fc1  = (const float*)d_in[2];
    const float* g_bn1  = (const float*)d_in[3];
    const float* be_bn1 = (const float*)d_in[4];
    const float* w_g    = (const float*)d_in[5];
    const float* b_g    = (const float*)d_in[6];
    const float* g_in   = (const float*)d_in[7];
    const float* be_in  = (const float*)d_in[8];
    const float* w_fc2  = (const float*)d_in[9];
    const float* b_fc2  = (const float*)d_in[10];
    const float* g_bn2  = (const float*)d_in[11];
    const float* be_bn2 = (const float*)d_in[12];
    const float* w_f1   = (const float*)d_in[13];
    const float* b_f1   = (const float*)d_in[14];
    const float* g_bnf1 = (const float*)d_in[15];
    const float* be_bnf1= (const float*)d_in[16];
    const float* w_f2   = (const float*)d_in[17];
    const float* b_f2   = (const float*)d_in[18];
    const float* g_bnf2 = (const float*)d_in[19];
    const float* be_bnf2= (const float*)d_in[20];
    float* outp = (float*)d_out;

    char* W = (char*)d_ws;
    // region S0 [0,50.3MB): xT -> (dminp/hminp during MR) -> y2 -> y4
    char* xT    = W;
    char* dminp = W;
    char* hminp = W + 16777216;
    char* y2    = W;
    char* y4    = W;
    // region S1: y1 -> x2
    char* y1 = W + 50331648;
    char* x2 = W + 50331648;
    // region S2/S3: hx, yg ; y3 spans both after they die
    char* hx = W + 100663296;
    char* yg = W + 201326592;
    char* y3 = W + 100663296;
    // misc
    char* M = W + 301989888;
    bf16*  Wb   = (bf16*)M;                    // 307200 B
    float* cf   = (float*)(M + 307200);        // 5 slots x 2048 f32
    float* part = (float*)(M + 348160);        // 5 slots x 49152 f32

    hipMemsetAsync(part, 0, 5 * 196608, stream);

    const float invBN = 1.f / (float)NVq, invIN = 1.f / (float)Sq;
    dim3 blk(256);

    wprep_k<<<600, blk, 0, stream>>>(w_fc1, w_g, w_fc2, w_f1, w_f2, Wb);
    tin_k<<<2048, blk, 0, stream>>>(x, xT);

    // fc1: 96 -> 96
    conv_k<192, 128, 96, 96, 0, false><<<dim3(2048, 1), blk, 0, stream>>>(
        xT, (const char*)Wb, b_fc1, nullptr, nullptr, (bf16*)y1, part);
    finalize_k<<<2, 64, 0, stream>>>(part, cf, g_bn1, be_bn1, 96, 96, 96, 0, invBN);

    // MRConv (partial residue-min fields, then fused combine + concat write)
    mr_dmin_k<<<dim3(8, 64, 2), dim3(192), 0, stream>>>(y1, cf, cf + 1024, dminp);
    mr_hmin_k<<<dim3(16, 32, 2), dim3(192), 0, stream>>>(y1, cf, cf + 1024, hminp);
    mr_p2_k<<<dim3(64, 32, 2), dim3(256), 0, stream>>>(y1, cf, cf + 1024, dminp, hminp, hx);

    // grapher conv: 192 -> 192, InstanceNorm stats (per b,c)
    conv_k<384, 192, 192, 192, 0, true><<<dim3(2048, 1), blk, 0, stream>>>(
        hx, (const char*)Wb + 24576, b_g, nullptr, nullptr, (bf16*)yg, part + 49152);
    finalize_k<<<6, 64, 0, stream>>>(part + 49152, cf + 2048, g_in, be_in, 384, 192, 192, 1, invIN);

    // fc2: 192 -> 96, loader = lrelu(A2*yg+B2) per (b,c)
    conv_k<384, 192, 96, 96, 2, false><<<dim3(2048, 1), blk, 0, stream>>>(
        yg, (const char*)Wb + 98304, b_fc2, cf + 2048, cf + 2048 + 1024, (bf16*)y2, part + 98304);
    finalize_k<<<2, 64, 0, stream>>>(part + 98304, cf + 4096, g_bn2, be_bn2, 96, 96, 96, 0, invBN);

    ewx2_k<<<2048, blk, 0, stream>>>(y2, cf + 4096, cf + 4096 + 1024, x, x2);

    // f1: 96 -> 384
    conv_k<192, 128, 384, 192, 0, false><<<dim3(2048, 2), blk, 0, stream>>>(
        x2, (const char*)Wb + 135168, b_f1, nullptr, nullptr, (bf16*)y3, part + 147456);
    finalize_k<<<6, 64, 0, stream>>>(part + 147456, cf + 6144, g_bnf1, be_bnf1, 384, 384, 192, 0, invBN);

    // f2: 384 -> 96, loader = lrelu(A4*y3+B4) per c
    conv_k<768, 384, 96, 96, 1, false><<<dim3(2048, 1), blk, 0, stream>>>(
        y3, (const char*)Wb + 233472, b_f2, cf + 6144, cf + 6144 + 1024, (bf16*)y4, part + 196608);
    finalize_k<<<2, 64, 0, stream>>>(part + 196608, cf + 8192, g_bnf2, be_bnf2, 96, 96, 96, 0, invBN);

    tout_k<<<2048, blk, 0, stream>>>(y4, cf + 8192, cf + 8192 + 1024, x2, outp);
}